// Round 1
// baseline (278.331 us; speedup 1.0000x reference)
//
#include <hip/hip_runtime.h>

// out[s, :] = W_tok[x[s], :] + b_tok[:] + W_pos[(S-1)-s, :] + b_pos[:]
// S = 8192, D = 1024 (= 256 float4), all fp32.
// One block per s; 256 threads; each thread handles one float4 (16 B).
__global__ void __launch_bounds__(256)
embedding_kernel(const int* __restrict__ x,
                 const float4* __restrict__ W_tok,
                 const float4* __restrict__ b_tok,
                 const float4* __restrict__ W_pos,
                 const float4* __restrict__ b_pos,
                 float4* __restrict__ out,
                 int S) {
    const int s = blockIdx.x;
    const int d = threadIdx.x;            // 0..255 float4 chunks = 1024 floats
    const int tok = x[s];                 // wave-uniform scalar load
    const int pos = (S - 1) - s;

    const float4 a  = W_tok[(size_t)tok * 256 + d];
    const float4 b  = W_pos[(size_t)pos * 256 + d];
    const float4 bt = b_tok[d];           // L2-resident (4 KB)
    const float4 bp = b_pos[d];           // L2-resident (4 KB)

    float4 r;
    r.x = a.x + b.x + bt.x + bp.x;
    r.y = a.y + b.y + bt.y + bp.y;
    r.z = a.z + b.z + bt.z + bp.z;
    r.w = a.w + b.w + bt.w + bp.w;

    out[(size_t)s * 256 + d] = r;
}

extern "C" void kernel_launch(void* const* d_in, const int* in_sizes, int n_in,
                              void* d_out, int out_size, void* d_ws, size_t ws_size,
                              hipStream_t stream) {
    const int*    x     = (const int*)   d_in[0];  // [8192] int32
    const float4* W_tok = (const float4*)d_in[1];  // [50257, 1024] f32
    const float4* b_tok = (const float4*)d_in[2];  // [1024] f32
    const float4* W_pos = (const float4*)d_in[3];  // [8192, 1024] f32
    const float4* b_pos = (const float4*)d_in[4];  // [1024] f32
    float4* out = (float4*)d_out;                  // [8192, 1024] f32

    const int S = in_sizes[0];                     // 8192

    embedding_kernel<<<S, 256, 0, stream>>>(x, W_tok, b_tok, W_pos, b_pos, out, S);
}

// Round 3
// 276.819 us; speedup vs baseline: 1.0055x; 1.0055x over previous
//
#include <hip/hip_runtime.h>

// out[s, :] = W_tok[x[s], :] + b_tok[:] + W_pos[(S-1)-s, :] + b_pos[:]
// S = 8192, D = 1024 floats (= 256 vec4 chunks), all fp32.
//
// Memory-bound: ~96 MB HBM traffic (32 MB W_tok gather + 32 MB W_pos stream
// + 32 MB out stream) -> ~15 us floor at 6.3 TB/s achievable.
//
// Native clang vector type: __builtin_nontemporal_* requires a vector of
// scalars, not HIP's struct float4.
typedef float v4f __attribute__((ext_vector_type(4)));

#define ROWS_PER_BLOCK 8

__global__ void __launch_bounds__(256)
embedding_kernel(const int* __restrict__ x,
                 const v4f* __restrict__ W_tok,
                 const v4f* __restrict__ b_tok,
                 const v4f* __restrict__ W_pos,
                 const v4f* __restrict__ b_pos,
                 v4f* __restrict__ out,
                 int S) {
    const int d = threadIdx.x;                       // fixed vec4 chunk 0..255
    const int s0 = blockIdx.x * ROWS_PER_BLOCK;

    // Biases: loaded once per thread (was in R1: once per row per thread).
    const v4f bt = b_tok[d];
    const v4f bp = b_pos[d];
    const v4f bsum = bt + bp;

    // Token ids up-front: uniform loads, all in flight together.
    int tok[ROWS_PER_BLOCK];
#pragma unroll
    for (int r = 0; r < ROWS_PER_BLOCK; ++r) tok[r] = x[s0 + r];

    // Issue all row loads back-to-back (ILP hides gather latency).
    v4f a[ROWS_PER_BLOCK], p[ROWS_PER_BLOCK];
#pragma unroll
    for (int r = 0; r < ROWS_PER_BLOCK; ++r) {
        a[r] = W_tok[(size_t)tok[r] * 256 + d];
        // W_pos is streamed exactly once -> nontemporal, don't pollute L2.
        p[r] = __builtin_nontemporal_load(&W_pos[(size_t)(S - 1 - (s0 + r)) * 256 + d]);
    }

#pragma unroll
    for (int r = 0; r < ROWS_PER_BLOCK; ++r) {
        v4f o = a[r] + p[r] + bsum;
        // out is write-once -> nontemporal store.
        __builtin_nontemporal_store(o, &out[(size_t)(s0 + r) * 256 + d]);
    }
}

extern "C" void kernel_launch(void* const* d_in, const int* in_sizes, int n_in,
                              void* d_out, int out_size, void* d_ws, size_t ws_size,
                              hipStream_t stream) {
    const int* x     = (const int*)d_in[0];        // [8192] int32
    const v4f* W_tok = (const v4f*)d_in[1];        // [50257, 1024] f32
    const v4f* b_tok = (const v4f*)d_in[2];        // [1024] f32
    const v4f* W_pos = (const v4f*)d_in[3];        // [8192, 1024] f32
    const v4f* b_pos = (const v4f*)d_in[4];        // [1024] f32
    v4f* out = (v4f*)d_out;                        // [8192, 1024] f32

    const int S = in_sizes[0];                     // 8192

    embedding_kernel<<<S / ROWS_PER_BLOCK, 256, 0, stream>>>(
        x, W_tok, b_tok, W_pos, b_pos, out, S);
}